// Round 2
// baseline (453.635 us; speedup 1.0000x reference)
//
#include <hip/hip_runtime.h>

// out[b,p,o] = sum_k W[po,k] * x[b,k] + bias[po]
// M=32, N=4096, K=16384. Memory-bound: W = 256 MB fp32 streamed once (~43 us floor).
// Depth-3 weight prefetch to cover ~900-cyc HBM latency (distance-1 was latency-bound at 2.6 TB/s).

#define KDIM 16384   // I0*I1
#define NPO 4096     // O0*O1
#define PO_TILE 8
#define KCHUNK 256   // 64 lanes * 4 floats
#define NITER 64     // KDIM / KCHUNK

__global__ __launch_bounds__(256, 2)
void trace_kernel(const float* __restrict__ x, const float* __restrict__ w,
                  const float* __restrict__ bias, float* __restrict__ out) {
  const int lane = threadIdx.x & 63;
  const int wave = threadIdx.x >> 6;          // 0..3
  const int po_base = blockIdx.x * PO_TILE;   // 8 po's per block
  const int b0 = wave * 8;                    // 8 batches per wave

  const float* wbase = w + (size_t)po_base * KDIM + (lane << 2);
  const float* xbase = x + (size_t)b0 * KDIM + (lane << 2);

  float acc[8][8];
#pragma unroll
  for (int i = 0; i < 8; ++i)
#pragma unroll
    for (int j = 0; j < 8; ++j) acc[i][j] = 0.f;

  float4 W0[8], W1[8], W2[8];   // named buffers: all indexing compile-time (no scratch)
  float4 X[8];

  auto load_w = [&](float4 (&WB)[8], int c) {
#pragma unroll
    for (int pp = 0; pp < 8; ++pp)
      WB[pp] = *reinterpret_cast<const float4*>(wbase + (size_t)pp * KDIM + (size_t)c * KCHUNK);
  };
  auto load_x = [&](int bb, int c) {
    X[bb] = *reinterpret_cast<const float4*>(xbase + (size_t)bb * KDIM + (size_t)c * KCHUNK);
  };

  // phase: FMA on chunk c using WB; per-bb reload X[bb] with x(c+1) right after last use;
  // then issue w(cw) into WB's successor slot (passed as WN).
  auto phase = [&](float4 (&WB)[8], int c, bool ldx, bool ldw, float4 (&WN)[8], int cw) {
#pragma unroll
    for (int bb = 0; bb < 8; ++bb) {
      float4 xv = X[bb];
      if (ldx) load_x(bb, c + 1);   // WAR broken by the xv copy -> load issues immediately
#pragma unroll
      for (int pp = 0; pp < 8; ++pp) {
        acc[bb][pp] += xv.x * WB[pp].x;
        acc[bb][pp] += xv.y * WB[pp].y;
        acc[bb][pp] += xv.z * WB[pp].z;
        acc[bb][pp] += xv.w * WB[pp].w;
      }
    }
    if (ldw) load_w(WN, cw);
  };

  // prologue: 3 weight chunks + x chunk 0 in flight
  load_w(W0, 0);
  load_w(W1, 1);
  load_w(W2, 2);
#pragma unroll
  for (int bb = 0; bb < 8; ++bb) load_x(bb, 0);

  // main: chunks 0..59, w prefetch runs 3 ahead (last issued: w62)
  for (int i = 0; i < 20; ++i) {
    const int c = i * 3;
    phase(W0, c,     true, true, W0, c + 3);
    phase(W1, c + 1, true, true, W1, c + 4);
    phase(W2, c + 2, true, true, W2, c + 5);
  }
  // drain: chunks 60..63
  phase(W0, 60, true,  true,  W0, 63);
  phase(W1, 61, true,  false, W1, 0);
  phase(W2, 62, true,  false, W2, 0);
  phase(W0, 63, false, false, W0, 0);

  // bias for this lane's output column
  const float bsv = bias[po_base + (lane & 7)];

  // lanes partition K; full 64-lane butterfly per element, lane e keeps element e
  const float* accf = &acc[0][0];
  float val = 0.f;
#pragma unroll
  for (int e = 0; e < 64; ++e) {
    float v = accf[e];
    v += __shfl_xor(v, 1);
    v += __shfl_xor(v, 2);
    v += __shfl_xor(v, 4);
    v += __shfl_xor(v, 8);
    v += __shfl_xor(v, 16);
    v += __shfl_xor(v, 32);
    val = (lane == e) ? v : val;
  }

  // element e = bb*8 + pp  ->  lane l writes (b0 + l>>3, po_base + (l&7))
  out[(size_t)(b0 + (lane >> 3)) * NPO + po_base + (lane & 7)] = val + bsv;
}

extern "C" void kernel_launch(void* const* d_in, const int* in_sizes, int n_in,
                              void* d_out, int out_size, void* d_ws, size_t ws_size,
                              hipStream_t stream) {
  const float* x    = (const float*)d_in[0];
  const float* wgt  = (const float*)d_in[1];
  const float* bias = (const float*)d_in[2];
  float* out = (float*)d_out;
  dim3 grid(NPO / PO_TILE);  // 512 blocks = 2 blocks/CU
  dim3 block(256);
  hipLaunchKernelGGL(trace_kernel, grid, block, 0, stream, x, wgt, bias, out);
}

// Round 3
// 146.578 us; speedup vs baseline: 3.0948x; 3.0948x over previous
//
#include <hip/hip_runtime.h>

// out[b,p,o] = sum_k W[po,k] * x[b,k] + bias[po]
// M=32, N=4096, K=16384. HBM floor: W = 256 MB fp32 once ~= 43 us.
// Structure: 256 blocks (1/CU) x 512 thr. Block = 16 po x 32 b.
// Per 256-k chunk: stage w(16KB)+x(32KB) into LDS (reg-staged, issue-early/
// write-late), double-buffered (96 KB). Waves = 4 bgroups x 2 po-halves,
// each lane acc[8][8], lanes partition k within chunk.

#define KDIM 16384
#define NPO  4096
#define POT  16
#define NCH  64
#define CHK  256
#define HALF_F 12288   // f32 per LDS half: w 16*256 + x 32*256
#define XOFF 4096      // f32 offset of x region within a half

__global__ __launch_bounds__(512, 2)
void trace_kernel(const float* __restrict__ x, const float* __restrict__ w,
                  const float* __restrict__ bias, float* __restrict__ out) {
  __shared__ float lds[2 * HALF_F];   // 96 KB

  const int t      = threadIdx.x;
  const int lane   = t & 63;
  const int wv     = t >> 6;     // 0..7
  const int bgroup = wv & 3;     // batches 8*bgroup .. +7
  const int pohalf = wv >> 2;    // 0..1 -> po 8*pohalf .. +7
  const int po_base = blockIdx.x * POT;

  // --- staging plan: thread stages 6 float4 per chunk at flat f32 idx t*4 + i*2048 ---
  const float* src[6];
  int loff[6];
#pragma unroll
  for (int i = 0; i < 6; ++i) {
    const int f = t * 4 + i * 2048;
    loff[i] = f;
    if (f < XOFF) {                       // w region: row r, col
      const int r = f >> 8, col = f & 255;
      src[i] = w + (size_t)(po_base + r) * KDIM + col;
    } else {                              // x region: batch b, col
      const int g = f - XOFF;
      const int b = g >> 8, col = g & 255;
      src[i] = x + (size_t)b * KDIM + col;
    }
  }

  // prologue: stage chunk 0 into half 0
  {
    float4 st0[6];
#pragma unroll
    for (int i = 0; i < 6; ++i)
      st0[i] = *reinterpret_cast<const float4*>(src[i]);
#pragma unroll
    for (int i = 0; i < 6; ++i)
      *reinterpret_cast<float4*>(&lds[loff[i]]) = st0[i];
  }
  __syncthreads();

  float acc[8][8];
#pragma unroll
  for (int i = 0; i < 8; ++i)
#pragma unroll
    for (int j = 0; j < 8; ++j) acc[i][j] = 0.f;

  float4 st[6];

  for (int c = 0; c < NCH; ++c) {
    const int half = c & 1;
    const float* wl = &lds[half * HALF_F + (pohalf * 8) * CHK + lane * 4];
    const float* xl = &lds[half * HALF_F + XOFF + (bgroup * 8) * CHK + lane * 4];

    // issue next chunk's global loads EARLY (land during FMA phase)
    if (c + 1 < NCH) {
#pragma unroll
      for (int i = 0; i < 6; ++i)
        st[i] = *reinterpret_cast<const float4*>(src[i] + (size_t)(c + 1) * CHK);
    }

    float4 wf[8], xf[8];
#pragma unroll
    for (int p = 0; p < 8; ++p)
      wf[p] = *reinterpret_cast<const float4*>(wl + p * CHK);
#pragma unroll
    for (int b = 0; b < 8; ++b)
      xf[b] = *reinterpret_cast<const float4*>(xl + b * CHK);

#pragma unroll
    for (int b = 0; b < 8; ++b)
#pragma unroll
      for (int p = 0; p < 8; ++p) {
        acc[b][p] += xf[b].x * wf[p].x;
        acc[b][p] += xf[b].y * wf[p].y;
        acc[b][p] += xf[b].z * wf[p].z;
        acc[b][p] += xf[b].w * wf[p].w;
      }

    // write staged regs to the other half (vmcnt drains here, after ~full phase)
    if (c + 1 < NCH) {
      float* dst = &lds[(half ^ 1) * HALF_F];
#pragma unroll
      for (int i = 0; i < 6; ++i)
        *reinterpret_cast<float4*>(&dst[loff[i]]) = st[i];
    }
    __syncthreads();
  }

  // epilogue: lanes partition k -> butterfly each of the 64 acc elements;
  // lane e keeps element e = b*8 + p
  const float bsv = bias[po_base + pohalf * 8 + (lane & 7)];
  const float* accf = &acc[0][0];
  float val = 0.f;
#pragma unroll
  for (int e = 0; e < 64; ++e) {
    float v = accf[e];
    v += __shfl_xor(v, 1);
    v += __shfl_xor(v, 2);
    v += __shfl_xor(v, 4);
    v += __shfl_xor(v, 8);
    v += __shfl_xor(v, 16);
    v += __shfl_xor(v, 32);
    val = (lane == e) ? v : val;
  }

  out[(size_t)(bgroup * 8 + (lane >> 3)) * NPO + po_base + pohalf * 8 + (lane & 7)] =
      val + bsv;
}

extern "C" void kernel_launch(void* const* d_in, const int* in_sizes, int n_in,
                              void* d_out, int out_size, void* d_ws, size_t ws_size,
                              hipStream_t stream) {
  const float* x    = (const float*)d_in[0];
  const float* wgt  = (const float*)d_in[1];
  const float* bias = (const float*)d_in[2];
  float* out = (float*)d_out;
  dim3 grid(NPO / POT);   // 256 blocks = 1/CU
  dim3 block(512);
  hipLaunchKernelGGL(trace_kernel, grid, block, 0, stream, x, wgt, bias, out);
}

// Round 4
// 80.883 us; speedup vs baseline: 5.6085x; 1.8122x over previous
//
#include <hip/hip_runtime.h>

// out[b,po] = sum_k W[po,k] * x[b,k] + bias[po];  M=32, N=4096, K=16384.
// HBM floor: W 256 MB fp32 streamed once (~43 us; less with L3 hits).
// MFMA bf16 structure: grid 256 (16 po/block), 512 thr = 8 waves
//   = 2 b-tiles x 4 k-quarters. Per 256-k chunk: stage w+x fp32->bf16 into
//   padded LDS (stride 264), dbuf, 1 barrier/chunk. Each wave: 2x
//   mfma_f32_16x16x32_bf16 into one f32x4 acc. Epilogue: LDS k-reduce.

typedef __attribute__((ext_vector_type(8))) __bf16 bf16x8;
typedef __attribute__((ext_vector_type(4))) float f32x4;

#define KDIM 16384
#define NPO  4096
#define POT  16
#define CHK  256
#define NCH  64      // KDIM / CHK
#define WSTR 264     // padded LDS k-stride (bf16 elems): 264*2B = 528B -> banks spread

__device__ inline bf16x8 cvt8(float4 a, float4 b) {
  bf16x8 r;
  r[0] = (__bf16)a.x; r[1] = (__bf16)a.y; r[2] = (__bf16)a.z; r[3] = (__bf16)a.w;
  r[4] = (__bf16)b.x; r[5] = (__bf16)b.y; r[6] = (__bf16)b.z; r[7] = (__bf16)b.w;
  return r;
}

__global__ __launch_bounds__(512, 2)
void trace_kernel(const float* __restrict__ x, const float* __restrict__ w,
                  const float* __restrict__ bias, float* __restrict__ out) {
  __shared__ __bf16 wbuf[2][16 * WSTR];   // 16.5 KB
  __shared__ __bf16 xbuf[2][32 * WSTR];   // 33 KB
  __shared__ float  red[8 * 64 * 4];      // 8 KB k-reduction scratch

  const int t    = threadIdx.x;
  const int lane = t & 63;
  const int wv   = t >> 6;      // 0..7
  const int btile = wv >> 2;    // 0..1  (16 batches each)
  const int kq    = wv & 3;     // k-quarter within chunk (64 k each)
  const int po_base = blockIdx.x * POT;

  // ---- staging coords (whole block cooperates) ----
  const int wrow = t >> 5, wcol = (t & 31) * 8;    // w: 16 rows x 256 k
  const int xrow = t >> 4, xcol = (t & 15) * 16;   // x: 32 rows x 256 k
  const float* wg = w + (size_t)(po_base + wrow) * KDIM + wcol;
  const float* xg = x + (size_t)xrow * KDIM + xcol;
  const int woff = wrow * WSTR + wcol;
  const int xoff = xrow * WSTR + xcol;

  // ---- fragment coords ----
  const int lrow = lane & 15, lhi = lane >> 4;
  const int fk  = kq * 64 + lhi * 8;               // lane's k-base within chunk
  const int wfo = lrow * WSTR + fk;                // B-frag (w): col = lane&15
  const int xfo = (btile * 16 + lrow) * WSTR + fk; // A-frag (x): row = lane&15

  f32x4 acc = {0.f, 0.f, 0.f, 0.f};

  // prologue: stage chunk 0 into half 0
  {
    float4 a0 = *(const float4*)(wg);
    float4 a1 = *(const float4*)(wg + 4);
    float4 c0 = *(const float4*)(xg);
    float4 c1 = *(const float4*)(xg + 4);
    float4 c2 = *(const float4*)(xg + 8);
    float4 c3 = *(const float4*)(xg + 12);
    *(bf16x8*)&wbuf[0][woff]     = cvt8(a0, a1);
    *(bf16x8*)&xbuf[0][xoff]     = cvt8(c0, c1);
    *(bf16x8*)&xbuf[0][xoff + 8] = cvt8(c2, c3);
  }
  __syncthreads();

  for (int c = 0; c < NCH; ++c) {
    const int h = c & 1;
    float4 a0, a1, c0, c1, c2, c3;
    const bool pf = (c + 1 < NCH);
    if (pf) {  // issue next chunk's global loads EARLY (land during this phase)
      const float* wp = wg + (size_t)(c + 1) * CHK;
      const float* xp = xg + (size_t)(c + 1) * CHK;
      a0 = *(const float4*)(wp);
      a1 = *(const float4*)(wp + 4);
      c0 = *(const float4*)(xp);
      c1 = *(const float4*)(xp + 4);
      c2 = *(const float4*)(xp + 8);
      c3 = *(const float4*)(xp + 12);
    }

    // fragments + MFMA (A = x rows, B = w rows as K x N; same lane->k rule
    // on both operands so any within-window k-permutation cancels)
    bf16x8 bf0 = *(const bf16x8*)&wbuf[h][wfo];
    bf16x8 bf1 = *(const bf16x8*)&wbuf[h][wfo + 32];
    bf16x8 af0 = *(const bf16x8*)&xbuf[h][xfo];
    bf16x8 af1 = *(const bf16x8*)&xbuf[h][xfo + 32];
    acc = __builtin_amdgcn_mfma_f32_16x16x32_bf16(af0, bf0, acc, 0, 0, 0);
    acc = __builtin_amdgcn_mfma_f32_16x16x32_bf16(af1, bf1, acc, 0, 0, 0);

    if (pf) {  // convert + write-late into the other half (vmcnt drains here)
      *(bf16x8*)&wbuf[h ^ 1][woff]     = cvt8(a0, a1);
      *(bf16x8*)&xbuf[h ^ 1][xoff]     = cvt8(c0, c1);
      *(bf16x8*)&xbuf[h ^ 1][xoff + 8] = cvt8(c2, c3);
    }
    __syncthreads();
  }

  // ---- epilogue: reduce the 4 k-quarter partials per b-tile ----
  red[wv * 256 + lane * 4 + 0] = acc[0];
  red[wv * 256 + lane * 4 + 1] = acc[1];
  red[wv * 256 + lane * 4 + 2] = acc[2];
  red[wv * 256 + lane * 4 + 3] = acc[3];
  __syncthreads();

  const int bt2 = t >> 8;          // 0..1
  const int ln2 = (t >> 2) & 63;   // lane of the source waves
  const int rg  = t & 3;           // reg index
  const int base = bt2 * 4 * 256 + ln2 * 4 + rg;
  float v = red[base] + red[base + 256] + red[base + 512] + red[base + 768];
  // verified D layout (m89/m91): col = lane&15 (po), row = (lane>>4)*4 + reg (b)
  const int row = (ln2 >> 4) * 4 + rg;
  const int col = ln2 & 15;
  out[(size_t)(bt2 * 16 + row) * NPO + po_base + col] = v + bias[po_base + col];
}

extern "C" void kernel_launch(void* const* d_in, const int* in_sizes, int n_in,
                              void* d_out, int out_size, void* d_ws, size_t ws_size,
                              hipStream_t stream) {
  const float* x    = (const float*)d_in[0];
  const float* wgt  = (const float*)d_in[1];
  const float* bias = (const float*)d_in[2];
  float* out = (float*)d_out;
  dim3 grid(NPO / POT);   // 256 blocks = 1/CU
  dim3 block(512);
  hipLaunchKernelGGL(trace_kernel, grid, block, 0, stream, x, wgt, bias, out);
}

// Round 5
// 71.908 us; speedup vs baseline: 6.3086x; 1.1248x over previous
//
#include <hip/hip_runtime.h>

// out[b,po] = sum_k W[po,k] * x[b,k] + bias[po];  M=32, N=4096, K=16384.
// HBM floor: W 256 MB fp32 streamed once (~43 us, less with L3 hits).
// Structure: 256 blocks (1/CU, 16 po) x 512 thr = 8 waves (2 b-tiles x 4 k-quarters).
// Per 256-k chunk: distance-2 register prefetch -> cvt bf16 -> padded LDS dbuf;
// RAW s_barrier + lgkmcnt(0) only (no vmcnt drain) so prefetch loads stay in
// flight across barriers. 2x mfma_f32_16x16x32_bf16 per wave per chunk.

typedef __attribute__((ext_vector_type(8))) __bf16 bf16x8;
typedef __attribute__((ext_vector_type(4))) float f32x4;

#define KDIM 16384
#define NPO  4096
#define POT  16
#define CHK  256
#define NCH  64      // KDIM / CHK
#define WSTR 264     // padded LDS k-stride (bf16): 528 B -> banks spread

__device__ inline bf16x8 cvt8(float4 a, float4 b) {
  bf16x8 r;
  r[0] = (__bf16)a.x; r[1] = (__bf16)a.y; r[2] = (__bf16)a.z; r[3] = (__bf16)a.w;
  r[4] = (__bf16)b.x; r[5] = (__bf16)b.y; r[6] = (__bf16)b.z; r[7] = (__bf16)b.w;
  return r;
}

__global__ __launch_bounds__(512, 2)
void trace_kernel(const float* __restrict__ x, const float* __restrict__ w,
                  const float* __restrict__ bias, float* __restrict__ out) {
  __shared__ __bf16 wbuf[2][16 * WSTR];   // 16.5 KB
  __shared__ __bf16 xbuf[2][32 * WSTR];   // 33 KB
  __shared__ float  red[8 * 64 * 4];      // 8 KB k-reduction scratch

  const int t    = threadIdx.x;
  const int lane = t & 63;
  const int wv   = t >> 6;      // 0..7
  const int btile = wv >> 2;    // 0..1 (16 batches each)
  const int kq    = wv & 3;     // k-quarter within chunk
  const int po_base = blockIdx.x * POT;

  // staging coords (block cooperates): w 16x256, x 32x256 per chunk
  const int wrow = t >> 5, wcol = (t & 31) * 8;
  const int xrow = t >> 4, xcol = (t & 15) * 16;
  const float* wg = w + (size_t)(po_base + wrow) * KDIM + wcol;
  const float* xg = x + (size_t)xrow * KDIM + xcol;
  const int woff = wrow * WSTR + wcol;
  const int xoff = xrow * WSTR + xcol;

  // fragment coords (A = x rows, B = w rows; same lane->k rule both operands)
  const int lrow = lane & 15, lhi = lane >> 4;
  const int fk  = kq * 64 + lhi * 8;
  const int wfo = lrow * WSTR + fk;
  const int xfo = (btile * 16 + lrow) * WSTR + fk;

  f32x4 acc = {0.f, 0.f, 0.f, 0.f};

#define ISSUE(R, c) do {                                   \
    const float* wp_ = wg + (size_t)(c) * CHK;             \
    const float* xp_ = xg + (size_t)(c) * CHK;             \
    R[0] = *(const float4*)(wp_);                          \
    R[1] = *(const float4*)(wp_ + 4);                      \
    R[2] = *(const float4*)(xp_);                          \
    R[3] = *(const float4*)(xp_ + 4);                      \
    R[4] = *(const float4*)(xp_ + 8);                      \
    R[5] = *(const float4*)(xp_ + 12);                     \
  } while (0)

#define WRITE_LDS(R, h) do {                               \
    *(bf16x8*)&wbuf[h][woff]     = cvt8(R[0], R[1]);       \
    *(bf16x8*)&xbuf[h][xoff]     = cvt8(R[2], R[3]);       \
    *(bf16x8*)&xbuf[h][xoff + 8] = cvt8(R[4], R[5]);       \
  } while (0)

#define COMPUTE(h) do {                                    \
    bf16x8 bf0 = *(const bf16x8*)&wbuf[h][wfo];            \
    bf16x8 bf1 = *(const bf16x8*)&wbuf[h][wfo + 32];       \
    bf16x8 af0 = *(const bf16x8*)&xbuf[h][xfo];            \
    bf16x8 af1 = *(const bf16x8*)&xbuf[h][xfo + 32];       \
    acc = __builtin_amdgcn_mfma_f32_16x16x32_bf16(af0, bf0, acc, 0, 0, 0); \
    acc = __builtin_amdgcn_mfma_f32_16x16x32_bf16(af1, bf1, acc, 0, 0, 0); \
  } while (0)

  // lgkmcnt(0) ensures our ds ops (incl. writes) done before barrier;
  // NO vmcnt drain -> in-flight global loads survive the barrier.
#define BARRIER() do {                                     \
    asm volatile("s_waitcnt lgkmcnt(0)" ::: "memory");     \
    __builtin_amdgcn_s_barrier();                          \
  } while (0)

  float4 ra[6], rb[6];

  // prologue: chunk0 -> LDS[0]; chunk1 in flight in ra
  ISSUE(ra, 0);
  WRITE_LDS(ra, 0);          // vmcnt waits ra only
  ISSUE(ra, 1);
  BARRIER();

  for (int c = 0; c < NCH; c += 2) {
    // even phase: compute chunk c from LDS[0]
    if (c + 2 < NCH) ISSUE(rb, c + 2);
    COMPUTE(0);
    WRITE_LDS(ra, 1);        // chunk c+1; compiler waits vmcnt(6) (rb in flight)
    BARRIER();
    // odd phase: compute chunk c+1 from LDS[1]
    if (c + 3 < NCH) ISSUE(ra, c + 3);
    COMPUTE(1);
    if (c + 2 < NCH) WRITE_LDS(rb, 0);   // chunk c+2
    BARRIER();
  }

#undef ISSUE
#undef WRITE_LDS
#undef COMPUTE
#undef BARRIER

  // epilogue: reduce 4 k-quarter partials per b-tile
  red[wv * 256 + lane * 4 + 0] = acc[0];
  red[wv * 256 + lane * 4 + 1] = acc[1];
  red[wv * 256 + lane * 4 + 2] = acc[2];
  red[wv * 256 + lane * 4 + 3] = acc[3];
  __syncthreads();

  const int bt2 = t >> 8;          // 0..1
  const int ln2 = (t >> 2) & 63;   // source-wave lane
  const int rg  = t & 3;           // reg index
  const int base = bt2 * 4 * 256 + ln2 * 4 + rg;
  float v = red[base] + red[base + 256] + red[base + 512] + red[base + 768];
  // verified D layout (m89/m91): col = lane&15 (po), row = (lane>>4)*4 + reg (b)
  const int row = (ln2 >> 4) * 4 + rg;
  const int col = ln2 & 15;
  out[(size_t)(bt2 * 16 + row) * NPO + po_base + col] = v + bias[po_base + col];
}

extern "C" void kernel_launch(void* const* d_in, const int* in_sizes, int n_in,
                              void* d_out, int out_size, void* d_ws, size_t ws_size,
                              hipStream_t stream) {
  const float* x    = (const float*)d_in[0];
  const float* wgt  = (const float*)d_in[1];
  const float* bias = (const float*)d_in[2];
  float* out = (float*)d_out;
  dim3 grid(NPO / POT);   // 256 blocks = 1/CU
  dim3 block(512);
  hipLaunchKernelGGL(trace_kernel, grid, block, 0, stream, x, wgt, bias, out);
}

// Round 6
// 56.119 us; speedup vs baseline: 8.0835x; 1.2813x over previous
//
#include <hip/hip_runtime.h>

// out[b,po] = sum_k W[po,k]*x[b,k] + bias[po];  B=32, NPO=4096, K=16384.
// 3 kernels: (1) precast x->bf16 (1MB in d_ws), (2) main GEMM: 256 blocks
// (128 po-groups x 2 k-halves; kh=blockIdx&1 so each XCD's blocks share one
// x half-slice -> L2-resident), 512 thr, POT=32, K-half 8192 in 32 chunks of
// 256; distance-2 reg prefetch -> bf16 LDS dbuf, raw s_barrier (no vmcnt
// drain); 8 waves = 2 btile x 2 potile x 2 kq, 4x mfma 16x16x32 per chunk;
// fp32 partials to d_ws, (3) combine adds k-halves + bias (deterministic).

typedef __attribute__((ext_vector_type(8))) __bf16 bf16x8;
typedef __attribute__((ext_vector_type(4))) __bf16 bf16x4;
typedef __attribute__((ext_vector_type(4))) float f32x4;

#define KDIM 16384
#define NPO  4096
#define POT  32
#define CHK  256
#define KH   8192
#define NCHH 32      // chunks per k-half
#define WSTR 264     // padded LDS k-stride (bf16): 528 B

__device__ inline bf16x8 cvt8(float4 a, float4 b) {
  bf16x8 r;
  r[0] = (__bf16)a.x; r[1] = (__bf16)a.y; r[2] = (__bf16)a.z; r[3] = (__bf16)a.w;
  r[4] = (__bf16)b.x; r[5] = (__bf16)b.y; r[6] = (__bf16)b.z; r[7] = (__bf16)b.w;
  return r;
}

__global__ __launch_bounds__(256)
void precast_x(const float* __restrict__ x, __bf16* __restrict__ xbf) {
  const int i = blockIdx.x * 256 + threadIdx.x;   // 131072 float4s
  float4 v = reinterpret_cast<const float4*>(x)[i];
  bf16x4 o;
  o[0] = (__bf16)v.x; o[1] = (__bf16)v.y; o[2] = (__bf16)v.z; o[3] = (__bf16)v.w;
  reinterpret_cast<bf16x4*>(xbf)[i] = o;
}

__global__ __launch_bounds__(512, 2)
void trace_main(const __bf16* __restrict__ xbf, const float* __restrict__ w,
                float* __restrict__ part) {
  __shared__ __bf16 wbuf[2][32 * WSTR];   // 33 KB
  __shared__ __bf16 xbuf[2][32 * WSTR];   // 33 KB
  __shared__ float  red[2048];            // 8 KB

  const int t    = threadIdx.x;
  const int lane = t & 63;
  const int wv   = t >> 6;        // 0..7
  const int btile  = wv & 1;      // 16 batches
  const int potile = (wv >> 1) & 1;
  const int kq     = wv >> 2;     // 128-k quarter-half
  const int kh    = blockIdx.x & 1;    // all blocks of an XCD share parity
  const int group = blockIdx.x >> 1;   // po group (32 rows)
  const int po_base = group * POT;

  // staging coords: both tiles are 32 rows x 256 cols; 16 elems/thread
  const int row_s = t >> 4;
  const int col_s = (t & 15) * 16;
  const float*  wg = w   + (size_t)(po_base + row_s) * KDIM + (size_t)kh * KH + col_s;
  const __bf16* xg = xbf + (size_t)row_s * KDIM + (size_t)kh * KH + col_s;
  const int soff = row_s * WSTR + col_s;

  // fragment coords (A = x, B = w; same lane->k rule on both operands)
  const int lrow = lane & 15, lhi = lane >> 4;
  const int fk  = kq * 128 + lhi * 8;
  const int wfo = (potile * 16 + lrow) * WSTR + fk;
  const int xfo = (btile * 16 + lrow) * WSTR + fk;

  f32x4 acc = {0.f, 0.f, 0.f, 0.f};

#define ISSUE(W4, X2, c) do {                              \
    const float*  wp_ = wg + (size_t)(c) * CHK;            \
    const __bf16* xp_ = xg + (size_t)(c) * CHK;            \
    W4[0] = *(const float4*)(wp_);                         \
    W4[1] = *(const float4*)(wp_ + 4);                     \
    W4[2] = *(const float4*)(wp_ + 8);                     \
    W4[3] = *(const float4*)(wp_ + 12);                    \
    X2[0] = *(const bf16x8*)(xp_);                         \
    X2[1] = *(const bf16x8*)(xp_ + 8);                     \
  } while (0)

#define WRITE_LDS(W4, X2, h) do {                          \
    *(bf16x8*)&wbuf[h][soff]     = cvt8(W4[0], W4[1]);     \
    *(bf16x8*)&wbuf[h][soff + 8] = cvt8(W4[2], W4[3]);     \
    *(bf16x8*)&xbuf[h][soff]     = X2[0];                  \
    *(bf16x8*)&xbuf[h][soff + 8] = X2[1];                  \
  } while (0)

#define COMPUTE(h) do {                                    \
    _Pragma("unroll")                                      \
    for (int j = 0; j < 4; ++j) {                          \
      bf16x8 bf_ = *(const bf16x8*)&wbuf[h][wfo + j * 32]; \
      bf16x8 af_ = *(const bf16x8*)&xbuf[h][xfo + j * 32]; \
      acc = __builtin_amdgcn_mfma_f32_16x16x32_bf16(af_, bf_, acc, 0, 0, 0); \
    }                                                      \
  } while (0)

  // lgkmcnt(0): our ds writes/reads done; NO vmcnt drain -> prefetch survives barrier
#define BARRIER() do {                                     \
    asm volatile("s_waitcnt lgkmcnt(0)" ::: "memory");     \
    __builtin_amdgcn_s_barrier();                          \
  } while (0)

  float4 raw[4], rbw[4];
  bf16x8 rax[2], rbx[2];

  // prologue: chunk0 -> LDS[0]; chunk1 in flight
  ISSUE(raw, rax, 0);
  WRITE_LDS(raw, rax, 0);
  ISSUE(raw, rax, 1);
  BARRIER();

  for (int c = 0; c < NCHH; c += 2) {
    if (c + 2 < NCHH) ISSUE(rbw, rbx, c + 2);
    COMPUTE(0);
    WRITE_LDS(raw, rax, 1);            // chunk c+1 (vmcnt counted: rb in flight)
    BARRIER();
    if (c + 3 < NCHH) ISSUE(raw, rax, c + 3);
    COMPUTE(1);
    if (c + 2 < NCHH) WRITE_LDS(rbw, rbx, 0);   // chunk c+2
    BARRIER();
  }

#undef ISSUE
#undef WRITE_LDS
#undef COMPUTE
#undef BARRIER

  // epilogue: reduce the 2 kq partials per (btile,potile) tile
  red[wv * 256 + lane * 4 + 0] = acc[0];
  red[wv * 256 + lane * 4 + 1] = acc[1];
  red[wv * 256 + lane * 4 + 2] = acc[2];
  red[wv * 256 + lane * 4 + 3] = acc[3];
  __syncthreads();

#pragma unroll
  for (int i0 = 0; i0 < 2; ++i0) {
    const int i    = i0 * 512 + t;     // 0..1023
    const int tile = i >> 8;           // potile*2 + btile
    const int slot = i & 255;
    const float v = red[tile * 256 + slot] + red[(tile + 4) * 256 + slot];
    const int ln = slot >> 2, rg = slot & 3;
    // D layout (verified m89/m91): col = lane&15 (po), row = (lane>>4)*4 + reg (b)
    const int b  = (tile & 1) * 16 + (ln >> 4) * 4 + rg;
    const int pl = (tile >> 1) * 16 + (ln & 15);
    part[((size_t)(kh * 128 + group) * 32 + b) * 32 + pl] = v;
  }
}

__global__ __launch_bounds__(256)
void combine(const float* __restrict__ part, const float* __restrict__ bias,
             float* __restrict__ out) {
  const int i = blockIdx.x * 256 + threadIdx.x;   // 0..131071: (g*32+b)*32+pl
  const int pl = i & 31, b = (i >> 5) & 31, g = i >> 10;
  const float v = part[i] + part[131072 + i] + bias[g * 32 + pl];
  out[(size_t)b * NPO + g * 32 + pl] = v;
}

extern "C" void kernel_launch(void* const* d_in, const int* in_sizes, int n_in,
                              void* d_out, int out_size, void* d_ws, size_t ws_size,
                              hipStream_t stream) {
  const float* x    = (const float*)d_in[0];
  const float* wgt  = (const float*)d_in[1];
  const float* bias = (const float*)d_in[2];
  float* out = (float*)d_out;

  __bf16* xbf = (__bf16*)d_ws;                          // 1 MB
  float*  part = (float*)((char*)d_ws + (1 << 20));     // 1 MB (2 k-halves)

  hipLaunchKernelGGL(precast_x, dim3(512), dim3(256), 0, stream, x, xbf);
  hipLaunchKernelGGL(trace_main, dim3(256), dim3(512), 0, stream, xbf, wgt, part);
  hipLaunchKernelGGL(combine, dim3(512), dim3(256), 0, stream, part, bias, out);
}